// Round 1
// baseline (3026.852 us; speedup 1.0000x reference)
//
#include <hip/hip_runtime.h>
#include <cstddef>
#include <cstdint>

#define D_MODEL 1024
#define D_INNER 2048
#define D_STATE 16
#define D_CONV  4
#define DT_RANK 64
#define BATCH   2
#define SEQLEN  2048
#define MROWS   (BATCH * SEQLEN)   // 4096

// ---------------------------------------------------------------------------
// Fused residual-add + RMSNorm. One block per row (4096 rows), 256 threads.
// Writes residual (output 1) and normalized hs (workspace).
// ---------------------------------------------------------------------------
__global__ __launch_bounds__(256) void add_rmsnorm_kernel(
    const float* __restrict__ x, const float* __restrict__ res,
    const float* __restrict__ w, float* __restrict__ res_out,
    float* __restrict__ hs_out)
{
    int row = blockIdx.x;
    size_t base = (size_t)row * D_MODEL;
    float v[4];
    float ss = 0.f;
#pragma unroll
    for (int i = 0; i < 4; i++) {
        int c = threadIdx.x + i * 256;
        float t = x[base + c] + res[base + c];
        v[i] = t;
        ss += t * t;
    }
#pragma unroll
    for (int off = 32; off > 0; off >>= 1) ss += __shfl_down(ss, off, 64);
    __shared__ float sred[4];
    if ((threadIdx.x & 63) == 0) sred[threadIdx.x >> 6] = ss;
    __syncthreads();
    float tot = sred[0] + sred[1] + sred[2] + sred[3];
    float inv = rsqrtf(tot / (float)D_MODEL + 1e-5f);
#pragma unroll
    for (int i = 0; i < 4; i++) {
        int c = threadIdx.x + i * 256;
        res_out[base + c] = v[i];
        hs_out[base + c] = v[i] * inv * w[c];
    }
}

// ---------------------------------------------------------------------------
// Generic tiled f32 GEMM: C[M,N] = act(A[M,K] @ B[K,N] + bias)
// 64x64 tile, BK=16, 256 threads, 4x4 per thread, float4 LDS reads.
// mode 0: none; mode 1: +bias then softplus.
// ---------------------------------------------------------------------------
#define BM 64
#define BN 64
#define BK 16

__global__ __launch_bounds__(256) void gemm_f32(
    const float* __restrict__ A, const float* __restrict__ B,
    float* __restrict__ C, int M, int N, int K,
    int lda, int ldb, int ldc, const float* __restrict__ bias, int mode)
{
    __shared__ __align__(16) float As[BK][BM + 4];  // stride 68 floats: 16B-aligned rows, <=2-way conflicts
    __shared__ __align__(16) float Bs[BK][BN];

    int tx = threadIdx.x & 15;
    int ty = threadIdx.x >> 4;
    int m0 = blockIdx.y * BM;
    int n0 = blockIdx.x * BN;

    float acc[4][4] = {};

    for (int k0 = 0; k0 < K; k0 += BK) {
        // stage A tile (64 rows x 16 k), transposed into As[k][m]
        {
            int kk = threadIdx.x & 15;
            int mm = threadIdx.x >> 4;
#pragma unroll
            for (int i = 0; i < 4; i++) {
                int m = m0 + mm + i * 16;
                int k = k0 + kk;
                float v = (m < M && k < K) ? A[(size_t)m * lda + k] : 0.f;
                As[kk][mm + i * 16] = v;
            }
        }
        // stage B tile (16 k x 64 n)
        {
            int n  = threadIdx.x & 63;
            int kk = threadIdx.x >> 6;  // 0..3
#pragma unroll
            for (int i = 0; i < 4; i++) {
                int k = k0 + kk + i * 4;
                int nn = n0 + n;
                float v = (k < K && nn < N) ? B[(size_t)k * ldb + nn] : 0.f;
                Bs[kk + i * 4][n] = v;
            }
        }
        __syncthreads();
#pragma unroll
        for (int k = 0; k < BK; k++) {
            float4 a = *reinterpret_cast<const float4*>(&As[k][ty * 4]);
            float4 b = *reinterpret_cast<const float4*>(&Bs[k][tx * 4]);
            float av[4] = {a.x, a.y, a.z, a.w};
            float bv[4] = {b.x, b.y, b.z, b.w};
#pragma unroll
            for (int i = 0; i < 4; i++)
#pragma unroll
                for (int j = 0; j < 4; j++)
                    acc[i][j] += av[i] * bv[j];
        }
        __syncthreads();
    }

#pragma unroll
    for (int i = 0; i < 4; i++) {
        int m = m0 + ty * 4 + i;
        if (m >= M) continue;
#pragma unroll
        for (int j = 0; j < 4; j++) {
            int n = n0 + tx * 4 + j;
            if (n >= N) continue;
            float v = acc[i][j];
            if (mode == 1) {
                v += bias[n];
                v = (v > 20.f) ? v : log1pf(__expf(v));
            }
            C[(size_t)m * ldc + n] = v;
        }
    }
}

// ---------------------------------------------------------------------------
// Causal depthwise conv1d (kernel 4) + bias + SiLU.
// Reads the x half of xz (columns 0..D_INNER-1 of [M, 2*D_INNER]).
// ---------------------------------------------------------------------------
__global__ __launch_bounds__(256) void conv_silu_kernel(
    const float* __restrict__ xz, const float* __restrict__ cw,
    const float* __restrict__ cb, float* __restrict__ xc)
{
    int idx = blockIdx.x * 256 + threadIdx.x;  // over MROWS * D_INNER
    int d = idx % D_INNER;
    int row = idx / D_INNER;  // b*L + l
    int l = row % SEQLEN;
    float s = cb[d];
#pragma unroll
    for (int k = 0; k < D_CONV; k++) {
        int ls = l + k - (D_CONV - 1);
        if (ls >= 0)
            s += xz[(size_t)(row + k - (D_CONV - 1)) * (2 * D_INNER) + d] * cw[d * D_CONV + k];
    }
    float sig = 1.f / (1.f + __expf(-s));
    xc[(size_t)row * D_INNER + d] = s * sig;
}

// ---------------------------------------------------------------------------
// Selective scan. 16 lanes per (b,d) pair (one lane per state n).
// h-recurrence: h = h*exp(dt*A) + dt*x*B ; y = sum_n h*C (shfl_xor reduce).
// Fused epilogue: out = (y + x*D_skip) * silu(z), written in-place over xc.
// ---------------------------------------------------------------------------
__global__ __launch_bounds__(256) void scan_kernel(
    const float* __restrict__ dt, float* __restrict__ xc,
    const float* __restrict__ xdbl, const float* __restrict__ xz,
    const float* __restrict__ A_log, const float* __restrict__ D_skip)
{
    int g = threadIdx.x >> 4;   // group within block
    int n = threadIdx.x & 15;   // state index
    int pair = blockIdx.x * 16 + g;
    int b = pair / D_INNER;
    int d = pair % D_INNER;

    float Ac = -__expf(A_log[d * D_STATE + n]);
    float dsk = D_skip[d];
    float h = 0.f;
    size_t rowbase = (size_t)b * SEQLEN;

    for (int l = 0; l < SEQLEN; l++) {
        size_t row = rowbase + l;
        float dtv = dt[row * D_INNER + d];
        float xv  = xc[row * D_INNER + d];
        float Bv  = xdbl[row * 96 + DT_RANK + n];
        float Cv  = xdbl[row * 96 + DT_RANK + D_STATE + n];
        float dA = __expf(dtv * Ac);
        h = h * dA + (dtv * xv) * Bv;
        float yv = h * Cv;
        yv += __shfl_xor(yv, 1, 16);
        yv += __shfl_xor(yv, 2, 16);
        yv += __shfl_xor(yv, 4, 16);
        yv += __shfl_xor(yv, 8, 16);
        if (n == 0) {
            float zv = xz[row * (2 * D_INNER) + D_INNER + d];
            float sig = 1.f / (1.f + __expf(-zv));
            xc[row * D_INNER + d] = (yv + xv * dsk) * (zv * sig);
        }
    }
}

// ---------------------------------------------------------------------------
extern "C" void kernel_launch(void* const* d_in, const int* in_sizes, int n_in,
                              void* d_out, int out_size, void* d_ws, size_t ws_size,
                              hipStream_t stream)
{
    const float* hidden     = (const float*)d_in[0];
    const float* resid      = (const float*)d_in[1];
    const float* norm_w     = (const float*)d_in[2];
    const float* in_proj_w  = (const float*)d_in[3];
    const float* conv_w     = (const float*)d_in[4];
    const float* conv_b     = (const float*)d_in[5];
    const float* x_proj_w   = (const float*)d_in[6];
    const float* dt_proj_w  = (const float*)d_in[7];
    const float* dt_proj_b  = (const float*)d_in[8];
    const float* A_log      = (const float*)d_in[9];
    const float* D_skip     = (const float*)d_in[10];
    const float* out_proj_w = (const float*)d_in[11];

    float* out     = (float*)d_out;                       // [4096,1024]
    float* res_out = out + (size_t)MROWS * D_MODEL;       // [4096,1024]

    // workspace layout (floats): 152.6 MB total
    float* ws   = (float*)d_ws;
    float* xz   = ws;                                     // M * 4096
    float* hs   = xz + (size_t)MROWS * 2 * D_INNER;       // M * 1024
    float* xc   = hs + (size_t)MROWS * D_MODEL;           // M * 2048 (x_conv, then y in-place)
    float* xdbl = xc + (size_t)MROWS * D_INNER;           // M * 96
    float* dt   = xdbl + (size_t)MROWS * 96;              // M * 2048

    // 1) residual add + RMSNorm
    add_rmsnorm_kernel<<<MROWS, 256, 0, stream>>>(hidden, resid, norm_w, res_out, hs);

    // 2) xz = hs @ in_proj_w   [4096,1024]@[1024,4096]
    {
        dim3 grid((2 * D_INNER + BN - 1) / BN, (MROWS + BM - 1) / BM);
        gemm_f32<<<grid, 256, 0, stream>>>(hs, in_proj_w, xz, MROWS, 2 * D_INNER, D_MODEL,
                                           D_MODEL, 2 * D_INNER, 2 * D_INNER, nullptr, 0);
    }

    // 3) causal conv + SiLU
    conv_silu_kernel<<<(MROWS * D_INNER) / 256, 256, 0, stream>>>(xz, conv_w, conv_b, xc);

    // 4) x_dbl = xc @ x_proj_w  [4096,2048]@[2048,96]
    {
        dim3 grid((96 + BN - 1) / BN, (MROWS + BM - 1) / BM);
        gemm_f32<<<grid, 256, 0, stream>>>(xc, x_proj_w, xdbl, MROWS, 96, D_INNER,
                                           D_INNER, 96, 96, nullptr, 0);
    }

    // 5) dt = softplus(x_dbl[:, :64] @ dt_proj_w + dt_proj_b)  [4096,64]@[64,2048]
    {
        dim3 grid((D_INNER + BN - 1) / BN, (MROWS + BM - 1) / BM);
        gemm_f32<<<grid, 256, 0, stream>>>(xdbl, dt_proj_w, dt, MROWS, D_INNER, DT_RANK,
                                           96, D_INNER, D_INNER, dt_proj_b, 1);
    }

    // 6) selective scan + gating epilogue (y written over xc)
    scan_kernel<<<(BATCH * D_INNER) / 16, 256, 0, stream>>>(dt, xc, xdbl, xz, A_log, D_skip);

    // 7) out = y @ out_proj_w  [4096,2048]@[2048,1024]
    {
        dim3 grid((D_MODEL + BN - 1) / BN, (MROWS + BM - 1) / BM);
        gemm_f32<<<grid, 256, 0, stream>>>(xc, out_proj_w, out, MROWS, D_MODEL, D_INNER,
                                           D_INNER, D_MODEL, D_MODEL, nullptr, 0);
    }
}

// Round 2
// 1622.525 us; speedup vs baseline: 1.8655x; 1.8655x over previous
//
#include <hip/hip_runtime.h>
#include <cstddef>
#include <cstdint>

#define D_MODEL 1024
#define D_INNER 2048
#define D_STATE 16
#define D_CONV  4
#define DT_RANK 64
#define BATCH   2
#define SEQLEN  2048
#define MROWS   (BATCH * SEQLEN)   // 4096
#define CS      64                 // scan chunk size
#define NC      (SEQLEN / CS)      // 32 chunks

// ---------------------------------------------------------------------------
// Fused residual-add + RMSNorm. One block per row (4096 rows), 256 threads.
// ---------------------------------------------------------------------------
__global__ __launch_bounds__(256) void add_rmsnorm_kernel(
    const float* __restrict__ x, const float* __restrict__ res,
    const float* __restrict__ w, float* __restrict__ res_out,
    float* __restrict__ hs_out)
{
    int row = blockIdx.x;
    size_t base = (size_t)row * D_MODEL;
    float v[4];
    float ss = 0.f;
#pragma unroll
    for (int i = 0; i < 4; i++) {
        int c = threadIdx.x + i * 256;
        float t = x[base + c] + res[base + c];
        v[i] = t;
        ss += t * t;
    }
#pragma unroll
    for (int off = 32; off > 0; off >>= 1) ss += __shfl_down(ss, off, 64);
    __shared__ float sred[4];
    if ((threadIdx.x & 63) == 0) sred[threadIdx.x >> 6] = ss;
    __syncthreads();
    float tot = sred[0] + sred[1] + sred[2] + sred[3];
    float inv = rsqrtf(tot / (float)D_MODEL + 1e-5f);
#pragma unroll
    for (int i = 0; i < 4; i++) {
        int c = threadIdx.x + i * 256;
        res_out[base + c] = v[i];
        hs_out[base + c] = v[i] * inv * w[c];
    }
}

// ---------------------------------------------------------------------------
// Generic tiled f32 GEMM: C[M,N] = act(A[M,K] @ B[K,N] + bias)
// 64x64 tile, BK=16, 256 threads, 4x4 per thread, float4 LDS reads.
// mode 0: none; mode 1: +bias then softplus.
// ---------------------------------------------------------------------------
#define BM 64
#define BN 64
#define BK 16

__global__ __launch_bounds__(256) void gemm_f32(
    const float* __restrict__ A, const float* __restrict__ B,
    float* __restrict__ C, int M, int N, int K,
    int lda, int ldb, int ldc, const float* __restrict__ bias, int mode)
{
    __shared__ __align__(16) float As[BK][BM + 4];
    __shared__ __align__(16) float Bs[BK][BN];

    int tx = threadIdx.x & 15;
    int ty = threadIdx.x >> 4;
    int m0 = blockIdx.y * BM;
    int n0 = blockIdx.x * BN;

    float acc[4][4] = {};

    for (int k0 = 0; k0 < K; k0 += BK) {
        {
            int kk = threadIdx.x & 15;
            int mm = threadIdx.x >> 4;
#pragma unroll
            for (int i = 0; i < 4; i++) {
                int m = m0 + mm + i * 16;
                int k = k0 + kk;
                float v = (m < M && k < K) ? A[(size_t)m * lda + k] : 0.f;
                As[kk][mm + i * 16] = v;
            }
        }
        {
            int n  = threadIdx.x & 63;
            int kk = threadIdx.x >> 6;
#pragma unroll
            for (int i = 0; i < 4; i++) {
                int k = k0 + kk + i * 4;
                int nn = n0 + n;
                float v = (k < K && nn < N) ? B[(size_t)k * ldb + nn] : 0.f;
                Bs[kk + i * 4][n] = v;
            }
        }
        __syncthreads();
#pragma unroll
        for (int k = 0; k < BK; k++) {
            float4 a = *reinterpret_cast<const float4*>(&As[k][ty * 4]);
            float4 b = *reinterpret_cast<const float4*>(&Bs[k][tx * 4]);
            float av[4] = {a.x, a.y, a.z, a.w};
            float bv[4] = {b.x, b.y, b.z, b.w};
#pragma unroll
            for (int i = 0; i < 4; i++)
#pragma unroll
                for (int j = 0; j < 4; j++)
                    acc[i][j] += av[i] * bv[j];
        }
        __syncthreads();
    }

#pragma unroll
    for (int i = 0; i < 4; i++) {
        int m = m0 + ty * 4 + i;
        if (m >= M) continue;
#pragma unroll
        for (int j = 0; j < 4; j++) {
            int n = n0 + tx * 4 + j;
            if (n >= N) continue;
            float v = acc[i][j];
            if (mode == 1) {
                v += bias[n];
                v = (v > 20.f) ? v : log1pf(__expf(v));
            }
            C[(size_t)m * ldc + n] = v;
        }
    }
}

// ---------------------------------------------------------------------------
// Causal depthwise conv1d (kernel 4) + bias + SiLU.
// ---------------------------------------------------------------------------
__global__ __launch_bounds__(256) void conv_silu_kernel(
    const float* __restrict__ xz, const float* __restrict__ cw,
    const float* __restrict__ cb, float* __restrict__ xc)
{
    int idx = blockIdx.x * 256 + threadIdx.x;
    int d = idx % D_INNER;
    int row = idx / D_INNER;
    int l = row % SEQLEN;
    float s = cb[d];
#pragma unroll
    for (int k = 0; k < D_CONV; k++) {
        int ls = l + k - (D_CONV - 1);
        if (ls >= 0)
            s += xz[(size_t)(row + k - (D_CONV - 1)) * (2 * D_INNER) + d] * cw[d * D_CONV + k];
    }
    float sig = 1.f / (1.f + __expf(-s));
    xc[(size_t)row * D_INNER + d] = s * sig;
}

// ---------------------------------------------------------------------------
// Chunked selective scan.
// Pass 1: per-chunk local scan (h0=0); store final local h and decay product P.
//   One thread per (b,chunk,d); h[16],P[16] in registers; dt/x coalesced,
//   B uniform (scalar-load path). State layout [b][c][n][d] for pass-2 coalescing.
// ---------------------------------------------------------------------------
__global__ __launch_bounds__(256) void scan_pass1(
    const float* __restrict__ dt, const float* __restrict__ xc,
    const float* __restrict__ xdbl, const float* __restrict__ A_log,
    float* __restrict__ hloc, float* __restrict__ Pk)
{
    int d = blockIdx.x * 256 + threadIdx.x;  // 0..D_INNER-1
    int c = blockIdx.y;
    int b = blockIdx.z;

    float A[D_STATE], h[D_STATE], P[D_STATE];
#pragma unroll
    for (int n = 0; n < D_STATE; n++) {
        A[n] = -__expf(A_log[d * D_STATE + n]);
        h[n] = 0.f;
        P[n] = 1.f;
    }

    size_t row = (size_t)b * SEQLEN + (size_t)c * CS;
    for (int t = 0; t < CS; t++, row++) {
        float dtv = dt[row * D_INNER + d];
        float xv  = xc[row * D_INNER + d];
        float dtx = dtv * xv;
        const float* bp = xdbl + row * 96 + DT_RANK;
#pragma unroll
        for (int n = 0; n < D_STATE; n++) {
            float dA = __expf(dtv * A[n]);
            P[n] *= dA;
            h[n] = h[n] * dA + dtx * bp[n];
        }
    }

    size_t base = (size_t)(b * NC + c) * D_STATE * D_INNER + d;
#pragma unroll
    for (int n = 0; n < D_STATE; n++) {
        hloc[base + (size_t)n * D_INNER] = h[n];
        Pk[base + (size_t)n * D_INNER]   = P[n];
    }
}

// ---------------------------------------------------------------------------
// Pass 2: sequential inter-chunk fix-up. One thread per (b,n,d); 32 steps.
// Overwrites hloc[c] with the INITIAL h for chunk c (in place).
// ---------------------------------------------------------------------------
__global__ __launch_bounds__(256) void scan_fix(
    float* __restrict__ hloc, const float* __restrict__ Pk)
{
    size_t i = (size_t)blockIdx.x * 256 + threadIdx.x;  // over B*16*D_INNER
    int b = (int)(i / (D_STATE * D_INNER));
    size_t nd = i % (D_STATE * D_INNER);
    float hrun = 0.f;
    for (int c = 0; c < NC; c++) {
        size_t idx = (size_t)(b * NC + c) * D_STATE * D_INNER + nd;
        float hl = hloc[idx];
        float p  = Pk[idx];
        hloc[idx] = hrun;
        hrun = p * hrun + hl;
    }
}

// ---------------------------------------------------------------------------
// Pass 3: recompute local scan seeded with h_init, reduce y = h·C, fused
// epilogue out = (y + x*D_skip)*silu(z) written over xc.
// ---------------------------------------------------------------------------
__global__ __launch_bounds__(256) void scan_pass3(
    const float* __restrict__ dt, float* __restrict__ xc,
    const float* __restrict__ xdbl, const float* __restrict__ xz,
    const float* __restrict__ A_log, const float* __restrict__ D_skip,
    const float* __restrict__ hinit)
{
    int d = blockIdx.x * 256 + threadIdx.x;
    int c = blockIdx.y;
    int b = blockIdx.z;

    float A[D_STATE], h[D_STATE];
    size_t base = (size_t)(b * NC + c) * D_STATE * D_INNER + d;
#pragma unroll
    for (int n = 0; n < D_STATE; n++) {
        A[n] = -__expf(A_log[d * D_STATE + n]);
        h[n] = hinit[base + (size_t)n * D_INNER];
    }
    float dsk = D_skip[d];

    size_t row = (size_t)b * SEQLEN + (size_t)c * CS;
    for (int t = 0; t < CS; t++, row++) {
        float dtv = dt[row * D_INNER + d];
        float xv  = xc[row * D_INNER + d];
        float dtx = dtv * xv;
        const float* bp = xdbl + row * 96 + DT_RANK;
        const float* cp = bp + D_STATE;
        float y = 0.f;
#pragma unroll
        for (int n = 0; n < D_STATE; n++) {
            float dA = __expf(dtv * A[n]);
            h[n] = h[n] * dA + dtx * bp[n];
            y += h[n] * cp[n];
        }
        float zv = xz[row * (2 * D_INNER) + D_INNER + d];
        float sig = 1.f / (1.f + __expf(-zv));
        xc[row * D_INNER + d] = (y + xv * dsk) * (zv * sig);
    }
}

// ---------------------------------------------------------------------------
extern "C" void kernel_launch(void* const* d_in, const int* in_sizes, int n_in,
                              void* d_out, int out_size, void* d_ws, size_t ws_size,
                              hipStream_t stream)
{
    const float* hidden     = (const float*)d_in[0];
    const float* resid      = (const float*)d_in[1];
    const float* norm_w     = (const float*)d_in[2];
    const float* in_proj_w  = (const float*)d_in[3];
    const float* conv_w     = (const float*)d_in[4];
    const float* conv_b     = (const float*)d_in[5];
    const float* x_proj_w   = (const float*)d_in[6];
    const float* dt_proj_w  = (const float*)d_in[7];
    const float* dt_proj_b  = (const float*)d_in[8];
    const float* A_log      = (const float*)d_in[9];
    const float* D_skip     = (const float*)d_in[10];
    const float* out_proj_w = (const float*)d_in[11];

    float* out     = (float*)d_out;                       // [4096,1024]
    float* res_out = out + (size_t)MROWS * D_MODEL;       // [4096,1024]

    // workspace layout (floats)
    float* ws   = (float*)d_ws;
    float* xz   = ws;                                     // M * 4096
    float* hs   = xz + (size_t)MROWS * 2 * D_INNER;       // M * 1024 (dead after step 2)
    float* xc   = hs + (size_t)MROWS * D_MODEL;           // M * 2048
    float* xdbl = xc + (size_t)MROWS * D_INNER;           // M * 96
    float* dt   = xdbl + (size_t)MROWS * 96;              // M * 2048

    // scan chunk state reuses hs (exactly 2 * B*NC*16*D_INNER floats = M*1024)
    float* hloc = hs;                                     // B*NC*16*D_INNER
    float* Pk   = hloc + (size_t)BATCH * NC * D_STATE * D_INNER;

    // 1) residual add + RMSNorm
    add_rmsnorm_kernel<<<MROWS, 256, 0, stream>>>(hidden, resid, norm_w, res_out, hs);

    // 2) xz = hs @ in_proj_w
    {
        dim3 grid((2 * D_INNER + BN - 1) / BN, (MROWS + BM - 1) / BM);
        gemm_f32<<<grid, 256, 0, stream>>>(hs, in_proj_w, xz, MROWS, 2 * D_INNER, D_MODEL,
                                           D_MODEL, 2 * D_INNER, 2 * D_INNER, nullptr, 0);
    }

    // 3) causal conv + SiLU
    conv_silu_kernel<<<(MROWS * D_INNER) / 256, 256, 0, stream>>>(xz, conv_w, conv_b, xc);

    // 4) x_dbl = xc @ x_proj_w
    {
        dim3 grid((96 + BN - 1) / BN, (MROWS + BM - 1) / BM);
        gemm_f32<<<grid, 256, 0, stream>>>(xc, x_proj_w, xdbl, MROWS, 96, D_INNER,
                                           D_INNER, 96, 96, nullptr, 0);
    }

    // 5) dt = softplus(x_dbl[:, :64] @ dt_proj_w + dt_proj_b)
    {
        dim3 grid((D_INNER + BN - 1) / BN, (MROWS + BM - 1) / BM);
        gemm_f32<<<grid, 256, 0, stream>>>(xdbl, dt_proj_w, dt, MROWS, D_INNER, DT_RANK,
                                           96, D_INNER, D_INNER, dt_proj_b, 1);
    }

    // 6) chunked selective scan
    {
        dim3 g1(D_INNER / 256, NC, BATCH);
        scan_pass1<<<g1, 256, 0, stream>>>(dt, xc, xdbl, A_log, hloc, Pk);
        scan_fix<<<(BATCH * D_STATE * D_INNER) / 256, 256, 0, stream>>>(hloc, Pk);
        scan_pass3<<<g1, 256, 0, stream>>>(dt, xc, xdbl, xz, A_log, D_skip, hloc);
    }

    // 7) out = y @ out_proj_w
    {
        dim3 grid((D_MODEL + BN - 1) / BN, (MROWS + BM - 1) / BM);
        gemm_f32<<<grid, 256, 0, stream>>>(xc, out_proj_w, out, MROWS, D_MODEL, D_INNER,
                                           D_INNER, D_MODEL, D_MODEL, nullptr, 0);
    }
}

// Round 3
// 531.279 us; speedup vs baseline: 5.6973x; 3.0540x over previous
//
#include <hip/hip_runtime.h>
#include <cstddef>
#include <cstdint>

#define D_MODEL 1024
#define D_INNER 2048
#define D_STATE 16
#define D_CONV  4
#define DT_RANK 64
#define BATCH   2
#define SEQLEN  2048
#define MROWS   (BATCH * SEQLEN)   // 4096
#define CS      64                 // scan chunk size
#define NC      (SEQLEN / CS)      // 32 chunks

typedef unsigned short u16;
typedef __attribute__((ext_vector_type(8))) short bf16x8;
typedef __attribute__((ext_vector_type(4))) float f32x4;

__device__ inline u16 f2bf(float v) {
    unsigned u = __float_as_uint(v);
    u += 0x7FFFu + ((u >> 16) & 1u);   // round-to-nearest-even
    return (u16)(u >> 16);
}

// async global->LDS, 16B per lane; dest = wave-uniform base + lane*16
__device__ inline void llds16(const u16* g, short* l) {
    __builtin_amdgcn_global_load_lds(
        (const __attribute__((address_space(1))) unsigned int*)g,
        (__attribute__((address_space(3))) unsigned int*)l, 16, 0, 0);
}

// ---------------------------------------------------------------------------
// Fused residual-add + RMSNorm. Writes residual (f32, output 1) and hs (bf16).
// ---------------------------------------------------------------------------
__global__ __launch_bounds__(256) void add_rmsnorm_kernel(
    const float* __restrict__ x, const float* __restrict__ res,
    const float* __restrict__ w, float* __restrict__ res_out,
    u16* __restrict__ hs_out)
{
    int row = blockIdx.x;
    size_t base = (size_t)row * D_MODEL;
    float v[4];
    float ss = 0.f;
#pragma unroll
    for (int i = 0; i < 4; i++) {
        int c = threadIdx.x + i * 256;
        float t = x[base + c] + res[base + c];
        v[i] = t;
        ss += t * t;
    }
#pragma unroll
    for (int off = 32; off > 0; off >>= 1) ss += __shfl_down(ss, off, 64);
    __shared__ float sred[4];
    if ((threadIdx.x & 63) == 0) sred[threadIdx.x >> 6] = ss;
    __syncthreads();
    float tot = sred[0] + sred[1] + sred[2] + sred[3];
    float inv = rsqrtf(tot / (float)D_MODEL + 1e-5f);
#pragma unroll
    for (int i = 0; i < 4; i++) {
        int c = threadIdx.x + i * 256;
        res_out[base + c] = v[i];
        hs_out[base + c] = f2bf(v[i] * inv * w[c]);
    }
}

// ---------------------------------------------------------------------------
// Transpose + f32->bf16: W[K][N] -> Wt[N][K].  Grid (N/32, K/32), 256 thr.
// ---------------------------------------------------------------------------
__global__ __launch_bounds__(256) void transpose_bf16_kernel(
    const float* __restrict__ W, u16* __restrict__ Wt, int K, int N)
{
    __shared__ float tile[32][33];
    int tx = threadIdx.x & 31, ty = threadIdx.x >> 5;  // 32x8
    int n0 = blockIdx.x * 32, k0 = blockIdx.y * 32;
#pragma unroll
    for (int i = 0; i < 32; i += 8)
        tile[ty + i][tx] = W[(size_t)(k0 + ty + i) * N + n0 + tx];
    __syncthreads();
#pragma unroll
    for (int i = 0; i < 32; i += 8)
        Wt[(size_t)(n0 + ty + i) * K + k0 + tx] = f2bf(tile[tx][ty + i]);
}

// ---------------------------------------------------------------------------
// bf16 MFMA GEMM: C[M][N] f32 = A[M][K] @ Bt[N][K]^T   (both bf16)
// 128x128x32 tile, 256 threads (4 waves, each a 64x64 quadrant via 4x4
// mfma_f32_16x16x32_bf16). global_load_lds 16B staging; XOR-swizzled LDS
// (chunk ^= (row>>1)&3) -> conflict-free ds_read_b128 fragment reads.
// Requires M,N % 128 == 0, K % 32 == 0.
// ---------------------------------------------------------------------------
__global__ __launch_bounds__(256) void gemm_bf16(
    const u16* __restrict__ A, const u16* __restrict__ Bt,
    float* __restrict__ C, int M, int N, int K, int lda, int ldb, int ldc)
{
    __shared__ __align__(16) short As[128 * 32];
    __shared__ __align__(16) short Bs[128 * 32];

    int w = threadIdx.x >> 6;
    int lane = threadIdx.x & 63;
    int wr = w >> 1, wc = w & 1;
    int m0 = blockIdx.y * 128;
    int n0 = blockIdx.x * 128;

    // staging geometry: wave w fills segments {2w, 2w+1} (1024B each) of A and B
    int cs = lane & 3;
    int rs0 = (2 * w) * 16 + (lane >> 2);
    int rs1 = rs0 + 16;
    int c0 = cs ^ ((rs0 >> 1) & 3);   // source chunk for swizzled slot
    int c1 = cs ^ ((rs1 >> 1) & 3);
    const u16* pA0 = A + (size_t)(m0 + rs0) * lda + c0 * 8;
    const u16* pA1 = A + (size_t)(m0 + rs1) * lda + c1 * 8;
    const u16* pB0 = Bt + (size_t)(n0 + rs0) * ldb + c0 * 8;
    const u16* pB1 = Bt + (size_t)(n0 + rs1) * ldb + c1 * 8;
    short* lA0 = As + (2 * w) * 512;
    short* lA1 = lA0 + 512;
    short* lB0 = Bs + (2 * w) * 512;
    short* lB1 = lB0 + 512;

    // fragment read offsets (shorts): A[m=lane&15][k=q*8+j], B[k][n=lane&15]
    int q = lane >> 4, mm = lane & 15;
    int offA[4], offB[4];
#pragma unroll
    for (int i = 0; i < 4; i++) {
        int rA = wr * 64 + i * 16 + mm;
        offA[i] = (rA * 4 + (q ^ ((rA >> 1) & 3))) * 8;
        int rB = wc * 64 + i * 16 + mm;
        offB[i] = (rB * 4 + (q ^ ((rB >> 1) & 3))) * 8;
    }

    f32x4 acc[4][4] = {};

    for (int k0 = 0; k0 < K; k0 += 32) {
        llds16(pA0, lA0);
        llds16(pA1, lA1);
        llds16(pB0, lB0);
        llds16(pB1, lB1);
        pA0 += 32; pA1 += 32; pB0 += 32; pB1 += 32;
        __syncthreads();   // compiler drains vmcnt before s_barrier
        bf16x8 af[4], bfr[4];
#pragma unroll
        for (int i = 0; i < 4; i++) af[i] = *reinterpret_cast<const bf16x8*>(As + offA[i]);
#pragma unroll
        for (int j = 0; j < 4; j++) bfr[j] = *reinterpret_cast<const bf16x8*>(Bs + offB[j]);
#pragma unroll
        for (int i = 0; i < 4; i++)
#pragma unroll
            for (int j = 0; j < 4; j++)
                acc[i][j] = __builtin_amdgcn_mfma_f32_16x16x32_bf16(af[i], bfr[j], acc[i][j], 0, 0, 0);
        __syncthreads();
    }

    // epilogue: C/D layout col=lane&15, row=q*4+reg
#pragma unroll
    for (int i = 0; i < 4; i++)
#pragma unroll
        for (int v = 0; v < 4; v++) {
            int row = m0 + wr * 64 + i * 16 + q * 4 + v;
            float* crow = C + (size_t)row * ldc + n0 + wc * 64 + mm;
#pragma unroll
            for (int j = 0; j < 4; j++)
                crow[j * 16] = acc[i][j][v];
        }
}

// ---------------------------------------------------------------------------
// f32 GEMM (small shapes): C = act(A @ B + bias). mode 1: softplus(+bias).
// ---------------------------------------------------------------------------
#define BM 64
#define BN 64
#define BK 16

__global__ __launch_bounds__(256) void gemm_f32(
    const float* __restrict__ A, const float* __restrict__ B,
    float* __restrict__ C, int M, int N, int K,
    int lda, int ldb, int ldc, const float* __restrict__ bias, int mode)
{
    __shared__ __align__(16) float As[BK][BM + 4];
    __shared__ __align__(16) float Bs[BK][BN];

    int tx = threadIdx.x & 15;
    int ty = threadIdx.x >> 4;
    int m0 = blockIdx.y * BM;
    int n0 = blockIdx.x * BN;

    float acc[4][4] = {};

    for (int k0 = 0; k0 < K; k0 += BK) {
        {
            int kk = threadIdx.x & 15;
            int mmm = threadIdx.x >> 4;
#pragma unroll
            for (int i = 0; i < 4; i++) {
                int m = m0 + mmm + i * 16;
                int k = k0 + kk;
                As[kk][mmm + i * 16] = (m < M && k < K) ? A[(size_t)m * lda + k] : 0.f;
            }
        }
        {
            int n = threadIdx.x & 63;
            int kk = threadIdx.x >> 6;
#pragma unroll
            for (int i = 0; i < 4; i++) {
                int k = k0 + kk + i * 4;
                int nn = n0 + n;
                Bs[kk + i * 4][n] = (k < K && nn < N) ? B[(size_t)k * ldb + nn] : 0.f;
            }
        }
        __syncthreads();
#pragma unroll
        for (int k = 0; k < BK; k++) {
            float4 a = *reinterpret_cast<const float4*>(&As[k][ty * 4]);
            float4 b = *reinterpret_cast<const float4*>(&Bs[k][tx * 4]);
            float av[4] = {a.x, a.y, a.z, a.w};
            float bv[4] = {b.x, b.y, b.z, b.w};
#pragma unroll
            for (int i = 0; i < 4; i++)
#pragma unroll
                for (int j = 0; j < 4; j++)
                    acc[i][j] += av[i] * bv[j];
        }
        __syncthreads();
    }

#pragma unroll
    for (int i = 0; i < 4; i++) {
        int m = m0 + ty * 4 + i;
        if (m >= M) continue;
#pragma unroll
        for (int j = 0; j < 4; j++) {
            int n = n0 + tx * 4 + j;
            if (n >= N) continue;
            float v = acc[i][j];
            if (mode == 1) {
                v += bias[n];
                v = (v > 20.f) ? v : log1pf(__expf(v));
            }
            C[(size_t)m * ldc + n] = v;
        }
    }
}

// split-K variant (for skinny x_proj): atomicAdd into pre-zeroed C
__global__ __launch_bounds__(256) void gemm_f32_splitk(
    const float* __restrict__ A, const float* __restrict__ B,
    float* __restrict__ C, int M, int N, int K,
    int lda, int ldb, int ldc, int kchunk)
{
    __shared__ __align__(16) float As[BK][BM + 4];
    __shared__ __align__(16) float Bs[BK][BN];

    int tx = threadIdx.x & 15;
    int ty = threadIdx.x >> 4;
    int m0 = blockIdx.y * BM;
    int n0 = blockIdx.x * BN;
    int kbeg = blockIdx.z * kchunk;
    int kend = kbeg + kchunk; if (kend > K) kend = K;

    float acc[4][4] = {};

    for (int k0 = kbeg; k0 < kend; k0 += BK) {
        {
            int kk = threadIdx.x & 15;
            int mmm = threadIdx.x >> 4;
#pragma unroll
            for (int i = 0; i < 4; i++) {
                int m = m0 + mmm + i * 16;
                int k = k0 + kk;
                As[kk][mmm + i * 16] = (m < M && k < kend) ? A[(size_t)m * lda + k] : 0.f;
            }
        }
        {
            int n = threadIdx.x & 63;
            int kk = threadIdx.x >> 6;
#pragma unroll
            for (int i = 0; i < 4; i++) {
                int k = k0 + kk + i * 4;
                int nn = n0 + n;
                Bs[kk + i * 4][n] = (k < kend && nn < N) ? B[(size_t)k * ldb + nn] : 0.f;
            }
        }
        __syncthreads();
#pragma unroll
        for (int k = 0; k < BK; k++) {
            float4 a = *reinterpret_cast<const float4*>(&As[k][ty * 4]);
            float4 b = *reinterpret_cast<const float4*>(&Bs[k][tx * 4]);
            float av[4] = {a.x, a.y, a.z, a.w};
            float bv[4] = {b.x, b.y, b.z, b.w};
#pragma unroll
            for (int i = 0; i < 4; i++)
#pragma unroll
                for (int j = 0; j < 4; j++)
                    acc[i][j] += av[i] * bv[j];
        }
        __syncthreads();
    }

#pragma unroll
    for (int i = 0; i < 4; i++) {
        int m = m0 + ty * 4 + i;
        if (m >= M) continue;
#pragma unroll
        for (int j = 0; j < 4; j++) {
            int n = n0 + tx * 4 + j;
            if (n >= N) continue;
            atomicAdd(&C[(size_t)m * ldc + n], acc[i][j]);
        }
    }
}

__global__ __launch_bounds__(256) void zero_kernel(float* p, int n)
{
    int i = blockIdx.x * 256 + threadIdx.x;
    if (i < n) p[i] = 0.f;
}

// ---------------------------------------------------------------------------
// Causal depthwise conv1d (kernel 4) + bias + SiLU.
// ---------------------------------------------------------------------------
__global__ __launch_bounds__(256) void conv_silu_kernel(
    const float* __restrict__ xz, const float* __restrict__ cw,
    const float* __restrict__ cb, float* __restrict__ xc)
{
    int idx = blockIdx.x * 256 + threadIdx.x;
    int d = idx % D_INNER;
    int row = idx / D_INNER;
    int l = row % SEQLEN;
    float s = cb[d];
#pragma unroll
    for (int k = 0; k < D_CONV; k++) {
        int ls = l + k - (D_CONV - 1);
        if (ls >= 0)
            s += xz[(size_t)(row + k - (D_CONV - 1)) * (2 * D_INNER) + d] * cw[d * D_CONV + k];
    }
    float sig = 1.f / (1.f + __expf(-s));
    xc[(size_t)row * D_INNER + d] = s * sig;
}

// ---------------------------------------------------------------------------
// Chunked selective scan (3 passes).
// ---------------------------------------------------------------------------
__global__ __launch_bounds__(256) void scan_pass1(
    const float* __restrict__ dt, const float* __restrict__ xc,
    const float* __restrict__ xdbl, const float* __restrict__ A_log,
    float* __restrict__ hloc, float* __restrict__ Pk)
{
    int d = blockIdx.x * 256 + threadIdx.x;
    int c = blockIdx.y;
    int b = blockIdx.z;

    float A[D_STATE], h[D_STATE], P[D_STATE];
#pragma unroll
    for (int n = 0; n < D_STATE; n++) {
        A[n] = -__expf(A_log[d * D_STATE + n]);
        h[n] = 0.f;
        P[n] = 1.f;
    }

    size_t row = (size_t)b * SEQLEN + (size_t)c * CS;
    for (int t = 0; t < CS; t++, row++) {
        float dtv = dt[row * D_INNER + d];
        float xv  = xc[row * D_INNER + d];
        float dtx = dtv * xv;
        const float* bp = xdbl + row * 96 + DT_RANK;
#pragma unroll
        for (int n = 0; n < D_STATE; n++) {
            float dA = __expf(dtv * A[n]);
            P[n] *= dA;
            h[n] = h[n] * dA + dtx * bp[n];
        }
    }

    size_t base = (size_t)(b * NC + c) * D_STATE * D_INNER + d;
#pragma unroll
    for (int n = 0; n < D_STATE; n++) {
        hloc[base + (size_t)n * D_INNER] = h[n];
        Pk[base + (size_t)n * D_INNER]   = P[n];
    }
}

__global__ __launch_bounds__(256) void scan_fix(
    float* __restrict__ hloc, const float* __restrict__ Pk)
{
    size_t i = (size_t)blockIdx.x * 256 + threadIdx.x;
    int b = (int)(i / (D_STATE * D_INNER));
    size_t nd = i % (D_STATE * D_INNER);
    float hrun = 0.f;
    for (int c = 0; c < NC; c++) {
        size_t idx = (size_t)(b * NC + c) * D_STATE * D_INNER + nd;
        float hl = hloc[idx];
        float p  = Pk[idx];
        hloc[idx] = hrun;
        hrun = p * hrun + hl;
    }
}

// Pass 3: seeded local scan, y = h·C, epilogue (y + x*D)*silu(z) -> y bf16.
// ybf aliases the (dead) x-half of the xz buffer: row stride 8192 u16.
__global__ __launch_bounds__(256) void scan_pass3(
    const float* __restrict__ dt, const float* __restrict__ xc,
    const float* __restrict__ xdbl, const float* __restrict__ xz,
    const float* __restrict__ A_log, const float* __restrict__ D_skip,
    const float* __restrict__ hinit, u16* ybf)
{
    int d = blockIdx.x * 256 + threadIdx.x;
    int c = blockIdx.y;
    int b = blockIdx.z;

    float A[D_STATE], h[D_STATE];
    size_t base = (size_t)(b * NC + c) * D_STATE * D_INNER + d;
#pragma unroll
    for (int n = 0; n < D_STATE; n++) {
        A[n] = -__expf(A_log[d * D_STATE + n]);
        h[n] = hinit[base + (size_t)n * D_INNER];
    }
    float dsk = D_skip[d];

    size_t row = (size_t)b * SEQLEN + (size_t)c * CS;
    for (int t = 0; t < CS; t++, row++) {
        float dtv = dt[row * D_INNER + d];
        float xv  = xc[row * D_INNER + d];
        float dtx = dtv * xv;
        const float* bp = xdbl + row * 96 + DT_RANK;
        const float* cp = bp + D_STATE;
        float y = 0.f;
#pragma unroll
        for (int n = 0; n < D_STATE; n++) {
            float dA = __expf(dtv * A[n]);
            h[n] = h[n] * dA + dtx * bp[n];
            y += h[n] * cp[n];
        }
        float zv = xz[row * (2 * D_INNER) + D_INNER + d];
        float sig = 1.f / (1.f + __expf(-zv));
        ybf[row * 8192 + d] = f2bf((y + xv * dsk) * (zv * sig));
    }
}

// ---------------------------------------------------------------------------
extern "C" void kernel_launch(void* const* d_in, const int* in_sizes, int n_in,
                              void* d_out, int out_size, void* d_ws, size_t ws_size,
                              hipStream_t stream)
{
    const float* hidden     = (const float*)d_in[0];
    const float* resid      = (const float*)d_in[1];
    const float* norm_w     = (const float*)d_in[2];
    const float* in_proj_w  = (const float*)d_in[3];
    const float* conv_w     = (const float*)d_in[4];
    const float* conv_b     = (const float*)d_in[5];
    const float* x_proj_w   = (const float*)d_in[6];
    const float* dt_proj_w  = (const float*)d_in[7];
    const float* dt_proj_b  = (const float*)d_in[8];
    const float* A_log      = (const float*)d_in[9];
    const float* D_skip     = (const float*)d_in[10];
    const float* out_proj_w = (const float*)d_in[11];

    float* out     = (float*)d_out;                       // [4096,1024]
    float* res_out = out + (size_t)MROWS * D_MODEL;       // [4096,1024]

    // workspace layout (f32 elements), total 152.6 MB — same as round 2:
    float* ws   = (float*)d_ws;
    float* xz   = ws;                                     // M*4096
    float* hsr  = xz + (size_t)MROWS * 2 * D_INNER;       // M*1024 multi-use region
    float* xc   = hsr + (size_t)MROWS * D_MODEL;          // M*2048
    float* xdbl = xc + (size_t)MROWS * D_INNER;           // M*96
    float* dt   = xdbl + (size_t)MROWS * 96;              // M*2048

    // overlays:
    u16* hs_bf = (u16*)hsr;                               // M*1024 bf16 (8.4MB)
    u16* ipwt  = hs_bf + (size_t)MROWS * D_MODEL;         // 4096*1024 bf16 (8.4MB)
    float* hloc = hsr;                                    // scan state (after in_proj)
    float* Pk   = hloc + (size_t)BATCH * NC * D_STATE * D_INNER;
    u16* ybf   = (u16*)xz;                                // y bf16, row stride 8192 (x-half dead)
    u16* opwt  = (u16*)xdbl;                              // 1024*2048 bf16 (xdbl+dt dead after pass3)

    // 1) residual add + RMSNorm (hs -> bf16)
    add_rmsnorm_kernel<<<MROWS, 256, 0, stream>>>(hidden, resid, norm_w, res_out, hs_bf);

    // 2) in_proj_w [1024][4096] -> bf16 [4096][1024]
    transpose_bf16_kernel<<<dim3(4096 / 32, 1024 / 32), 256, 0, stream>>>(in_proj_w, ipwt, 1024, 4096);

    // 3) xz = hs @ in_proj_w  (bf16 MFMA)
    gemm_bf16<<<dim3(4096 / 128, 4096 / 128), 256, 0, stream>>>(
        hs_bf, ipwt, xz, MROWS, 2 * D_INNER, D_MODEL, D_MODEL, D_MODEL, 2 * D_INNER);

    // 4) causal conv + SiLU
    conv_silu_kernel<<<(MROWS * D_INNER) / 256, 256, 0, stream>>>(xz, conv_w, conv_b, xc);

    // 5) x_dbl = xc @ x_proj_w  (split-K=4, atomic accumulate)
    zero_kernel<<<(MROWS * 96 + 255) / 256, 256, 0, stream>>>(xdbl, MROWS * 96);
    gemm_f32_splitk<<<dim3(2, MROWS / BM, 4), 256, 0, stream>>>(
        xc, x_proj_w, xdbl, MROWS, 96, D_INNER, D_INNER, 96, 96, 512);

    // 6) dt = softplus(x_dbl[:, :64] @ dt_proj_w + dt_proj_b)
    gemm_f32<<<dim3(D_INNER / BN, MROWS / BM), 256, 0, stream>>>(
        xdbl, dt_proj_w, dt, MROWS, D_INNER, DT_RANK, 96, D_INNER, D_INNER, dt_proj_b, 1);

    // 7) chunked selective scan; pass3 writes y (bf16) into xz x-half
    {
        dim3 g1(D_INNER / 256, NC, BATCH);
        scan_pass1<<<g1, 256, 0, stream>>>(dt, xc, xdbl, A_log, hloc, Pk);
        scan_fix<<<(BATCH * D_STATE * D_INNER) / 256, 256, 0, stream>>>(hloc, Pk);
        scan_pass3<<<g1, 256, 0, stream>>>(dt, xc, xdbl, xz, A_log, D_skip, hloc, ybf);
    }

    // 8) out_proj_w [2048][1024] -> bf16 [1024][2048]
    transpose_bf16_kernel<<<dim3(1024 / 32, 2048 / 32), 256, 0, stream>>>(out_proj_w, opwt, 2048, 1024);

    // 9) out = y @ out_proj_w  (bf16 MFMA; A row-stride 8192)
    gemm_bf16<<<dim3(1024 / 128, 4096 / 128), 256, 0, stream>>>(
        ybf, opwt, out, MROWS, D_MODEL, D_INNER, 2 * D_INNER * 2, D_INNER, D_MODEL);
}

// Round 5
// 420.589 us; speedup vs baseline: 7.1967x; 1.2632x over previous
//
#include <hip/hip_runtime.h>
#include <cstddef>
#include <cstdint>

#define D_MODEL 1024
#define D_INNER 2048
#define D_STATE 16
#define D_CONV  4
#define DT_RANK 64
#define BATCH   2
#define SEQLEN  2048
#define MROWS   (BATCH * SEQLEN)   // 4096
#define CS      64                 // scan chunk size
#define NC      (SEQLEN / CS)      // 32 chunks

typedef unsigned short u16;
typedef __attribute__((ext_vector_type(8))) short bf16x8;
typedef __attribute__((ext_vector_type(4))) float f32x4;

__device__ inline u16 f2bf(float v) {
    unsigned u = __float_as_uint(v);
    u += 0x7FFFu + ((u >> 16) & 1u);   // round-to-nearest-even
    return (u16)(u >> 16);
}
__device__ inline float bf2f(u16 v) {
    return __uint_as_float((unsigned)v << 16);
}

// async global->LDS, 16B per lane; LDS dest = wave-uniform base + lane*16
__device__ inline void llds16(const u16* g, short* l) {
    __builtin_amdgcn_global_load_lds(
        (const __attribute__((address_space(1))) unsigned int*)g,
        (__attribute__((address_space(3))) unsigned int*)l, 16, 0, 0);
}

// ---------------------------------------------------------------------------
// Fused residual-add + RMSNorm. Writes residual (f32, output 1) and hs (bf16).
// ---------------------------------------------------------------------------
__global__ __launch_bounds__(256) void add_rmsnorm_kernel(
    const float* __restrict__ x, const float* __restrict__ res,
    const float* __restrict__ w, float* __restrict__ res_out,
    u16* __restrict__ hs_out)
{
    int row = blockIdx.x;
    size_t base = (size_t)row * D_MODEL;
    float v[4];
    float ss = 0.f;
#pragma unroll
    for (int i = 0; i < 4; i++) {
        int c = threadIdx.x + i * 256;
        float t = x[base + c] + res[base + c];
        v[i] = t;
        ss += t * t;
    }
#pragma unroll
    for (int off = 32; off > 0; off >>= 1) ss += __shfl_down(ss, off, 64);
    __shared__ float sred[4];
    if ((threadIdx.x & 63) == 0) sred[threadIdx.x >> 6] = ss;
    __syncthreads();
    float tot = sred[0] + sred[1] + sred[2] + sred[3];
    float inv = rsqrtf(tot / (float)D_MODEL + 1e-5f);
#pragma unroll
    for (int i = 0; i < 4; i++) {
        int c = threadIdx.x + i * 256;
        res_out[base + c] = v[i];
        hs_out[base + c] = f2bf(v[i] * inv * w[c]);
    }
}

// ---------------------------------------------------------------------------
// Transpose + f32->bf16: W[K][N] -> Wt[N][K].  Grid (N/32, K/32), 256 thr.
// ---------------------------------------------------------------------------
__global__ __launch_bounds__(256) void transpose_bf16_kernel(
    const float* __restrict__ W, u16* __restrict__ Wt, int K, int N)
{
    __shared__ float tile[32][33];
    int tx = threadIdx.x & 31, ty = threadIdx.x >> 5;  // 32x8
    int n0 = blockIdx.x * 32, k0 = blockIdx.y * 32;
#pragma unroll
    for (int i = 0; i < 32; i += 8)
        tile[ty + i][tx] = W[(size_t)(k0 + ty + i) * N + n0 + tx];
    __syncthreads();
#pragma unroll
    for (int i = 0; i < 32; i += 8)
        Wt[(size_t)(n0 + ty + i) * K + k0 + tx] = f2bf(tile[tx][ty + i]);
}

// ---------------------------------------------------------------------------
// bf16 MFMA GEMM: C[M][N] f32 = A[M][K] @ Bt[N][K]^T   (both bf16)
// 128x128x32 tile, 4 waves (each 64x64 via 4x4 mfma_f32_16x16x32_bf16).
// global_load_lds 16B staging; XOR-swizzled LDS (chunk ^= (row>>1)&3).
// ---------------------------------------------------------------------------
__global__ __launch_bounds__(256) void gemm_bf16(
    const u16* __restrict__ A, const u16* __restrict__ Bt,
    float* __restrict__ C, int M, int N, int K, int lda, int ldb, int ldc)
{
    __shared__ __align__(16) short As[128 * 32];
    __shared__ __align__(16) short Bs[128 * 32];

    int w = threadIdx.x >> 6;
    int lane = threadIdx.x & 63;
    int wr = w >> 1, wc = w & 1;
    int m0 = blockIdx.y * 128;
    int n0 = blockIdx.x * 128;

    int cs = lane & 3;
    int rs0 = (2 * w) * 16 + (lane >> 2);
    int rs1 = rs0 + 16;
    int c0 = cs ^ ((rs0 >> 1) & 3);
    int c1 = cs ^ ((rs1 >> 1) & 3);
    const u16* pA0 = A + (size_t)(m0 + rs0) * lda + c0 * 8;
    const u16* pA1 = A + (size_t)(m0 + rs1) * lda + c1 * 8;
    const u16* pB0 = Bt + (size_t)(n0 + rs0) * ldb + c0 * 8;
    const u16* pB1 = Bt + (size_t)(n0 + rs1) * ldb + c1 * 8;
    short* lA0 = As + (2 * w) * 512;
    short* lA1 = lA0 + 512;
    short* lB0 = Bs + (2 * w) * 512;
    short* lB1 = lB0 + 512;

    int q = lane >> 4, mm = lane & 15;
    int offA[4], offB[4];
#pragma unroll
    for (int i = 0; i < 4; i++) {
        int rA = wr * 64 + i * 16 + mm;
        offA[i] = (rA * 4 + (q ^ ((rA >> 1) & 3))) * 8;
        int rB = wc * 64 + i * 16 + mm;
        offB[i] = (rB * 4 + (q ^ ((rB >> 1) & 3))) * 8;
    }

    f32x4 acc[4][4] = {};

    for (int k0 = 0; k0 < K; k0 += 32) {
        llds16(pA0, lA0);
        llds16(pA1, lA1);
        llds16(pB0, lB0);
        llds16(pB1, lB1);
        pA0 += 32; pA1 += 32; pB0 += 32; pB1 += 32;
        __syncthreads();
        bf16x8 af[4], bfr[4];
#pragma unroll
        for (int i = 0; i < 4; i++) af[i] = *reinterpret_cast<const bf16x8*>(As + offA[i]);
#pragma unroll
        for (int j = 0; j < 4; j++) bfr[j] = *reinterpret_cast<const bf16x8*>(Bs + offB[j]);
#pragma unroll
        for (int i = 0; i < 4; i++)
#pragma unroll
            for (int j = 0; j < 4; j++)
                acc[i][j] = __builtin_amdgcn_mfma_f32_16x16x32_bf16(af[i], bfr[j], acc[i][j], 0, 0, 0);
        __syncthreads();
    }

#pragma unroll
    for (int i = 0; i < 4; i++)
#pragma unroll
        for (int v = 0; v < 4; v++) {
            int row = m0 + wr * 64 + i * 16 + q * 4 + v;
            float* crow = C + (size_t)row * ldc + n0 + wc * 64 + mm;
#pragma unroll
            for (int j = 0; j < 4; j++)
                crow[j * 16] = acc[i][j][v];
        }
}

// ---------------------------------------------------------------------------
// x_proj split-K bf16 MFMA: part[z][M][96] = xcb[M][2048] @ xpwt[96][2048]^T
// over K-chunk z*128..z*128+128. Grid (1, M/128, 16). B rows >=96 clamped
// (finite garbage, never written). Partials reduced by reduce_xdbl.
// ---------------------------------------------------------------------------
__global__ __launch_bounds__(256) void gemm_bf16_xproj(
    const u16* __restrict__ A, const u16* __restrict__ Bt,
    float* __restrict__ part)
{
    __shared__ __align__(16) short As[128 * 32];
    __shared__ __align__(16) short Bs[128 * 32];

    int w = threadIdx.x >> 6;
    int lane = threadIdx.x & 63;
    int wr = w >> 1, wc = w & 1;
    int m0 = blockIdx.y * 128;
    int kbeg = blockIdx.z * 128;

    int cs = lane & 3;
    int rs0 = (2 * w) * 16 + (lane >> 2);
    int rs1 = rs0 + 16;
    int c0 = cs ^ ((rs0 >> 1) & 3);
    int c1 = cs ^ ((rs1 >> 1) & 3);
    int rb0 = rs0 > 95 ? 95 : rs0;
    int rb1 = rs1 > 95 ? 95 : rs1;
    const u16* pA0 = A + (size_t)(m0 + rs0) * 2048 + kbeg + c0 * 8;
    const u16* pA1 = A + (size_t)(m0 + rs1) * 2048 + kbeg + c1 * 8;
    const u16* pB0 = Bt + (size_t)rb0 * 2048 + kbeg + c0 * 8;
    const u16* pB1 = Bt + (size_t)rb1 * 2048 + kbeg + c1 * 8;
    short* lA0 = As + (2 * w) * 512;
    short* lA1 = lA0 + 512;
    short* lB0 = Bs + (2 * w) * 512;
    short* lB1 = lB0 + 512;

    int q = lane >> 4, mm = lane & 15;
    int offA[4], offB[4];
#pragma unroll
    for (int i = 0; i < 4; i++) {
        int rA = wr * 64 + i * 16 + mm;
        offA[i] = (rA * 4 + (q ^ ((rA >> 1) & 3))) * 8;
        int rB = wc * 64 + i * 16 + mm;
        offB[i] = (rB * 4 + (q ^ ((rB >> 1) & 3))) * 8;
    }

    f32x4 acc[4][4] = {};

    for (int k0 = 0; k0 < 128; k0 += 32) {
        llds16(pA0, lA0);
        llds16(pA1, lA1);
        llds16(pB0, lB0);
        llds16(pB1, lB1);
        pA0 += 32; pA1 += 32; pB0 += 32; pB1 += 32;
        __syncthreads();
        bf16x8 af[4], bfr[4];
#pragma unroll
        for (int i = 0; i < 4; i++) af[i] = *reinterpret_cast<const bf16x8*>(As + offA[i]);
#pragma unroll
        for (int j = 0; j < 4; j++) bfr[j] = *reinterpret_cast<const bf16x8*>(Bs + offB[j]);
#pragma unroll
        for (int i = 0; i < 4; i++)
#pragma unroll
            for (int j = 0; j < 4; j++)
                acc[i][j] = __builtin_amdgcn_mfma_f32_16x16x32_bf16(af[i], bfr[j], acc[i][j], 0, 0, 0);
        __syncthreads();
    }

    float* dst = part + (size_t)blockIdx.z * MROWS * 96;
#pragma unroll
    for (int i = 0; i < 4; i++)
#pragma unroll
        for (int v = 0; v < 4; v++) {
            int row = m0 + wr * 64 + i * 16 + q * 4 + v;
#pragma unroll
            for (int j = 0; j < 4; j++) {
                int col = wc * 64 + j * 16 + mm;
                if (col < 96) dst[(size_t)row * 96 + col] = acc[i][j][v];
            }
        }
}

__global__ __launch_bounds__(256) void reduce_xdbl(
    const float* __restrict__ part, float* __restrict__ xdbl)
{
    int i = blockIdx.x * 256 + threadIdx.x;  // over MROWS*96
    float s = 0.f;
#pragma unroll
    for (int z = 0; z < 16; z++) s += part[(size_t)z * MROWS * 96 + i];
    xdbl[i] = s;
}

// ---------------------------------------------------------------------------
// dt GEMM: dt[M][2048] = softplus(xdbl[M][96](cols 0..63) @ dtwt[2048][64]^T + b)
// K=64, single LDS stage. A staged f32->bf16 in-kernel; B via global_load_lds.
// Row-local layout [r][64] with chunk swizzle ch ^= (r&7) -> conflict-free b128.
// ---------------------------------------------------------------------------
__global__ __launch_bounds__(256) void gemm_dt(
    const float* __restrict__ xdbl, const u16* __restrict__ Bt,
    const float* __restrict__ bias, float* __restrict__ dtout)
{
    __shared__ __align__(16) short As[128 * 64];
    __shared__ __align__(16) short Bs[128 * 64];

    int w = threadIdx.x >> 6;
    int lane = threadIdx.x & 63;
    int wr = w >> 1, wc = w & 1;
    int m0 = blockIdx.y * 128;
    int n0 = blockIdx.x * 128;

    // A: 128 rows x 8 chunks of 8 shorts; thread t -> 4 chunks
#pragma unroll
    for (int it = 0; it < 4; it++) {
        int id = threadIdx.x + it * 256;
        int row = id >> 3, ch = id & 7;
        const float* src = xdbl + (size_t)(m0 + row) * 96 + ch * 8;
        float4 a = *reinterpret_cast<const float4*>(src);
        float4 b = *reinterpret_cast<const float4*>(src + 4);
        bf16x8 v;
        v[0] = (short)f2bf(a.x); v[1] = (short)f2bf(a.y);
        v[2] = (short)f2bf(a.z); v[3] = (short)f2bf(a.w);
        v[4] = (short)f2bf(b.x); v[5] = (short)f2bf(b.y);
        v[6] = (short)f2bf(b.z); v[7] = (short)f2bf(b.w);
        *reinterpret_cast<bf16x8*>(As + (size_t)(row * 8 + (ch ^ (row & 7))) * 8) = v;
    }
    // B: dest chunk id linear; slot (row,ch) holds source chunk ch^(row&7)
#pragma unroll
    for (int it = 0; it < 4; it++) {
        int id = w * 256 + it * 64 + lane;
        int row = id >> 3, ch = id & 7;
        int sch = ch ^ (row & 7);
        llds16(Bt + (size_t)(n0 + row) * 64 + sch * 8, Bs + (size_t)id * 8);
    }
    __syncthreads();

    int q = lane >> 4, mm = lane & 15;
    f32x4 acc[4][4] = {};
#pragma unroll
    for (int c = 0; c < 2; c++) {
        bf16x8 af[4], bfr[4];
#pragma unroll
        for (int i = 0; i < 4; i++) {
            int r = wr * 64 + i * 16 + mm;
            af[i] = *reinterpret_cast<const bf16x8*>(As + (size_t)(r * 8 + ((c * 4 + q) ^ (r & 7))) * 8);
        }
#pragma unroll
        for (int j = 0; j < 4; j++) {
            int n = wc * 64 + j * 16 + mm;
            bfr[j] = *reinterpret_cast<const bf16x8*>(Bs + (size_t)(n * 8 + ((c * 4 + q) ^ (n & 7))) * 8);
        }
#pragma unroll
        for (int i = 0; i < 4; i++)
#pragma unroll
            for (int j = 0; j < 4; j++)
                acc[i][j] = __builtin_amdgcn_mfma_f32_16x16x32_bf16(af[i], bfr[j], acc[i][j], 0, 0, 0);
    }

#pragma unroll
    for (int i = 0; i < 4; i++)
#pragma unroll
        for (int v = 0; v < 4; v++) {
            int row = m0 + wr * 64 + i * 16 + q * 4 + v;
#pragma unroll
            for (int j = 0; j < 4; j++) {
                int col = n0 + wc * 64 + j * 16 + mm;
                float val = acc[i][j][v] + bias[col];
                val = (val > 20.f) ? val : log1pf(__expf(val));
                dtout[(size_t)row * D_INNER + col] = val;
            }
        }
}

// ---------------------------------------------------------------------------
// Causal depthwise conv1d (kernel 4) + bias + SiLU -> bf16.
// ---------------------------------------------------------------------------
__global__ __launch_bounds__(256) void conv_silu_kernel(
    const float* __restrict__ xz, const float* __restrict__ cw,
    const float* __restrict__ cb, u16* __restrict__ xcb)
{
    int idx = blockIdx.x * 256 + threadIdx.x;
    int d = idx % D_INNER;
    int row = idx / D_INNER;
    int l = row % SEQLEN;
    float s = cb[d];
#pragma unroll
    for (int k = 0; k < D_CONV; k++) {
        int ls = l + k - (D_CONV - 1);
        if (ls >= 0)
            s += xz[(size_t)(row + k - (D_CONV - 1)) * (2 * D_INNER) + d] * cw[d * D_CONV + k];
    }
    float sig = 1.f / (1.f + __expf(-s));
    xcb[(size_t)row * D_INNER + d] = f2bf(s * sig);
}

// ---------------------------------------------------------------------------
// Chunked selective scan (3 passes). x is bf16 now.
// ---------------------------------------------------------------------------
__global__ __launch_bounds__(256) void scan_pass1(
    const float* __restrict__ dt, const u16* __restrict__ xcb,
    const float* __restrict__ xdbl, const float* __restrict__ A_log,
    float* __restrict__ hloc, float* __restrict__ Pk)
{
    int d = blockIdx.x * 256 + threadIdx.x;
    int c = blockIdx.y;
    int b = blockIdx.z;

    float A[D_STATE], h[D_STATE], P[D_STATE];
#pragma unroll
    for (int n = 0; n < D_STATE; n++) {
        A[n] = -__expf(A_log[d * D_STATE + n]);
        h[n] = 0.f;
        P[n] = 1.f;
    }

    size_t row = (size_t)b * SEQLEN + (size_t)c * CS;
    for (int t = 0; t < CS; t++, row++) {
        float dtv = dt[row * D_INNER + d];
        float xv  = bf2f(xcb[row * D_INNER + d]);
        float dtx = dtv * xv;
        const float* bp = xdbl + row * 96 + DT_RANK;
#pragma unroll
        for (int n = 0; n < D_STATE; n++) {
            float dA = __expf(dtv * A[n]);
            P[n] *= dA;
            h[n] = h[n] * dA + dtx * bp[n];
        }
    }

    size_t base = (size_t)(b * NC + c) * D_STATE * D_INNER + d;
#pragma unroll
    for (int n = 0; n < D_STATE; n++) {
        hloc[base + (size_t)n * D_INNER] = h[n];
        Pk[base + (size_t)n * D_INNER]   = P[n];
    }
}

__global__ __launch_bounds__(256) void scan_fix(
    float* __restrict__ hloc, const float* __restrict__ Pk)
{
    size_t i = (size_t)blockIdx.x * 256 + threadIdx.x;
    int b = (int)(i / (D_STATE * D_INNER));
    size_t nd = i % (D_STATE * D_INNER);
    float hrun = 0.f;
    for (int c = 0; c < NC; c++) {
        size_t idx = (size_t)(b * NC + c) * D_STATE * D_INNER + nd;
        float hl = hloc[idx];
        float p  = Pk[idx];
        hloc[idx] = hrun;
        hrun = p * hrun + hl;
    }
}

// Pass 3: seeded local scan, y = h·C, epilogue (y + x*D)*silu(z) -> y bf16.
// ybf aliases the (dead) x-half of the xz buffer: row stride 8192 u16.
__global__ __launch_bounds__(256) void scan_pass3(
    const float* __restrict__ dt, const u16* __restrict__ xcb,
    const float* __restrict__ xdbl, const float* __restrict__ xz,
    const float* __restrict__ A_log, const float* __restrict__ D_skip,
    const float* __restrict__ hinit, u16* ybf)
{
    int d = blockIdx.x * 256 + threadIdx.x;
    int c = blockIdx.y;
    int b = blockIdx.z;

    float A[D_STATE], h[D_STATE];
    size_t base = (size_t)(b * NC + c) * D_STATE * D_INNER + d;
#pragma unroll
    for (int n = 0; n < D_STATE; n++) {
        A[n] = -__expf(A_log[d * D_STATE + n]);
        h[n] = hinit[base + (size_t)n * D_INNER];
    }
    float dsk = D_skip[d];

    size_t row = (size_t)b * SEQLEN + (size_t)c * CS;
    for (int t = 0; t < CS; t++, row++) {
        float dtv = dt[row * D_INNER + d];
        float xv  = bf2f(xcb[row * D_INNER + d]);
        float dtx = dtv * xv;
        const float* bp = xdbl + row * 96 + DT_RANK;
        const float* cp = bp + D_STATE;
        float y = 0.f;
#pragma unroll
        for (int n = 0; n < D_STATE; n++) {
            float dA = __expf(dtv * A[n]);
            h[n] = h[n] * dA + dtx * bp[n];
            y += h[n] * cp[n];
        }
        float zv = xz[row * (2 * D_INNER) + D_INNER + d];
        float sig = 1.f / (1.f + __expf(-zv));
        ybf[row * 8192 + d] = f2bf((y + xv * dsk) * (zv * sig));
    }
}

// ---------------------------------------------------------------------------
extern "C" void kernel_launch(void* const* d_in, const int* in_sizes, int n_in,
                              void* d_out, int out_size, void* d_ws, size_t ws_size,
                              hipStream_t stream)
{
    const float* hidden     = (const float*)d_in[0];
    const float* resid      = (const float*)d_in[1];
    const float* norm_w     = (const float*)d_in[2];
    const float* in_proj_w  = (const float*)d_in[3];
    const float* conv_w     = (const float*)d_in[4];
    const float* conv_b     = (const float*)d_in[5];
    const float* x_proj_w   = (const float*)d_in[6];
    const float* dt_proj_w  = (const float*)d_in[7];
    const float* dt_proj_b  = (const float*)d_in[8];
    const float* A_log      = (const float*)d_in[9];
    const float* D_skip     = (const float*)d_in[10];
    const float* out_proj_w = (const float*)d_in[11];

    float* out     = (float*)d_out;                       // [4096,1024]
    float* res_out = out + (size_t)MROWS * D_MODEL;       // [4096,1024]

    // workspace regions (f32 elements), 152.5 MB total:
    float* ws    = (float*)d_ws;
    float* xz    = ws;                                    // M*4096 (67.1MB)
    float* hsr   = xz + (size_t)MROWS * 2 * D_INNER;      // M*1024 (16.8MB) multi-use
    float* xcreg = hsr + (size_t)MROWS * D_MODEL;         // M*2048 (33.5MB) multi-use
    float* xdbl  = xcreg + (size_t)MROWS * D_INNER;       // M*96
    float* dt    = xdbl + (size_t)MROWS * 96;             // M*2048

    // xcreg overlay map (float offsets within xcreg):
    //   [0,      98304)   xpwt  (x_proj^T bf16, dead after step 5)
    //   [98304,  163840)  dtwt  (dt_proj^T bf16, dead after step 6)
    //   [262144, 6553600) part  (split-K partials, dead after reduce)
    //   [0,      4194304) hloc+Pk (scan state, written step 7)
    //   [6553600,7602176) opwt  (out_proj^T bf16, live until step 8) -- MUST
    //                     sit past part's end; placing it at 4194304 (round 4)
    //                     let part clobber it -> NaN bf16 garbage into MFMA.
    u16* hs_bf = (u16*)hsr;                               // phase 1-3: hs bf16 (8.4MB)
    u16* ipwt  = hs_bf + (size_t)MROWS * D_MODEL;         // phase 2-3: in_proj^T bf16 (8.4MB)
    u16* xcb   = (u16*)hsr;                               // phase 4+: conv out bf16 (16.8MB)
    u16* xpwt  = (u16*)xcreg;                             // [96][2048]
    u16* dtwt  = xpwt + 96 * 2048;                        // [2048][64]
    float* part = xcreg + 262144;                         // 16*M*96 floats
    float* hloc = xcreg;                                  // scan state (after gemm_dt)
    float* Pk   = hloc + (size_t)BATCH * NC * D_STATE * D_INNER;
    u16* opwt  = (u16*)(xcreg + 6553600);                 // [1024][2048] bf16 (4MB)
    u16* ybf   = (u16*)xz;                                // y bf16, row stride 8192

    // 1) residual add + RMSNorm (hs -> bf16)
    add_rmsnorm_kernel<<<MROWS, 256, 0, stream>>>(hidden, resid, norm_w, res_out, hs_bf);

    // 2) weight transposes
    transpose_bf16_kernel<<<dim3(4096 / 32, 1024 / 32), 256, 0, stream>>>(in_proj_w, ipwt, 1024, 4096);
    transpose_bf16_kernel<<<dim3(96 / 32, 2048 / 32), 256, 0, stream>>>(x_proj_w, xpwt, 2048, 96);
    transpose_bf16_kernel<<<dim3(2048 / 32, 64 / 32), 256, 0, stream>>>(dt_proj_w, dtwt, 64, 2048);
    transpose_bf16_kernel<<<dim3(1024 / 32, 2048 / 32), 256, 0, stream>>>(out_proj_w, opwt, 2048, 1024);

    // 3) xz = hs @ in_proj_w  (bf16 MFMA)
    gemm_bf16<<<dim3(4096 / 128, 4096 / 128), 256, 0, stream>>>(
        hs_bf, ipwt, xz, MROWS, 2 * D_INNER, D_MODEL, D_MODEL, D_MODEL, 2 * D_INNER);

    // 4) causal conv + SiLU -> bf16 (overwrites hs_bf/ipwt, both dead)
    conv_silu_kernel<<<(MROWS * D_INNER) / 256, 256, 0, stream>>>(xz, conv_w, conv_b, xcb);

    // 5) x_dbl = x @ x_proj_w  (bf16 MFMA split-K=16 -> partials -> reduce)
    gemm_bf16_xproj<<<dim3(1, MROWS / 128, 16), 256, 0, stream>>>(xcb, xpwt, part);
    reduce_xdbl<<<(MROWS * 96) / 256, 256, 0, stream>>>(part, xdbl);

    // 6) dt = softplus(x_dbl[:, :64] @ dt_proj_w + b)  (bf16 MFMA, fused epi)
    gemm_dt<<<dim3(D_INNER / 128, MROWS / 128), 256, 0, stream>>>(xdbl, dtwt, dt_proj_b, dt);

    // 7) chunked selective scan (hloc/Pk overwrite xpwt/dtwt/part — all dead)
    {
        dim3 g1(D_INNER / 256, NC, BATCH);
        scan_pass1<<<g1, 256, 0, stream>>>(dt, xcb, xdbl, A_log, hloc, Pk);
        scan_fix<<<(BATCH * D_STATE * D_INNER) / 256, 256, 0, stream>>>(hloc, Pk);
        scan_pass3<<<g1, 256, 0, stream>>>(dt, xcb, xdbl, xz, A_log, D_skip, hloc, ybf);
    }

    // 8) out = y @ out_proj_w  (bf16 MFMA; A row-stride 8192)
    gemm_bf16<<<dim3(1024 / 128, 4096 / 128), 256, 0, stream>>>(
        ybf, opwt, out, MROWS, D_MODEL, D_INNER, 2 * D_INNER * 2, D_INNER, D_MODEL);
}